// Round 5
// baseline (125329.419 us; speedup 1.0000x reference)
//
#include <hip/hip_runtime.h>
#include <math.h>

// Leaky-integrator ESN, persistent-kernel, latency-optimized flag barrier.
//   x_t = 0.1*x_{t-1} + 0.9*tanh(W_in u_t + W x_{t-1} + b);  Y_t = W_out [x_t;1]
//
// W (16 MB) staged ONCE into LDS across 128 blocks (16 rows = 128 KB each; 1
// block/CU via LDS limit -> all 128 blocks resident at dispatch on 256 CUs).
// Per step: wave 0 polls 128 per-block flags (value == step, slots rotate
// mod 4 -> no RMW, no reset, 0xAA poison never matches), __threadfence()
// acquire (cross-XCD L2s are NOT coherent), gather x_{t-1} (8 KB) from a
// global double buffer, matvec own rows from LDS, release-store own flag
// (publishes the plain x-slice stores). Rotating designated block computes
// Y_{t-1} AFTER its flag store -> hidden under barrier latency.
//
// Protocol safety (audited): flag-slot overwrite needs skew>=4 (bound is 2);
// xbuf parity overwrite is gated on flags published only after every block's
// stage-read of that buffer. Watchdog: bounded spin ~0.25 s -> clean exit
// (wrong answer + counters instead of a dead container).
// R4 delta: inputs[t+1] prefetched into registers right after publish (wave-0
// lanes), overlapping the poll loop -> cold input load off the critical path.

#define T_STEPS 16384
#define NRES    2048
#define DIN     8
#define DOUT    8
#define NBLK    128
#define NTHR    512
#define ROWS    16                // NRES / NBLK
#define LEAK    0.9f
#define OML     0.1f              // 1 - LEAK
#define SPIN_LIMIT 400000         // ~0.25 s worst case; never hit when healthy

__launch_bounds__(NTHR, 1)
__global__ void esn_persistent(const float* __restrict__ inputs,
                               const float* __restrict__ W_in,
                               const float* __restrict__ W,
                               const float* __restrict__ bvec,
                               const float* __restrict__ W_out,
                               float* __restrict__ Y,
                               int*   __restrict__ flags,   // [4][NBLK], value = step+1
                               float* __restrict__ xbuf)    // [2][NRES]
{
    __shared__ float W_lds[ROWS][NRES];   // 128 KB: this block's rows of W
    __shared__ float x_lds[NRES];         // 8 KB: full x_{t-1}
    __shared__ float xin_lds[DIN];
    __shared__ float Win_lds[ROWS][DIN];
    __shared__ float b_lds[ROWS];
    __shared__ int   bail_s;

    const int b    = blockIdx.x;
    const int tid  = threadIdx.x;
    const int lid  = tid & 63;
    const int wv   = tid >> 6;            // wave 0..7
    const int row0 = b * ROWS;

    if (tid == 0) bail_s = 0;

    // ---- one-time staging: W rows, W_in rows, bias ----
    #pragma unroll
    for (int i = 0; i < ROWS * (NRES / 4) / NTHR; ++i) {       // 16 iters
        const int idx = i * NTHR + tid;
        const int r = idx >> 9, c = idx & 511;                 // NRES/4 = 512
        ((float4*)&W_lds[r][0])[c] =
            ((const float4*)(W + (size_t)(row0 + r) * NRES))[c];
    }
    if (tid < ROWS * DIN)
        Win_lds[tid >> 3][tid & 7] = W_in[(row0 + (tid >> 3)) * DIN + (tid & 7)];
    if (tid < ROWS) b_lds[tid] = bvec[row0 + tid];

    // input prefetch for step 0 (wave-0 lanes only)
    float xin_reg = (tid < DIN) ? inputs[tid] : 0.f;

    // readout of Y[tp] from x_lds (must hold x_tp); wave wv -> output wv.
    auto readout = [&](int tp) {
        const float* Wr = W_out + (size_t)wv * (NRES + 1);
        float a = 0.f;
        #pragma unroll
        for (int k = 0; k < NRES / 64; ++k)
            a += Wr[lid + 64 * k] * x_lds[lid + 64 * k];
        #pragma unroll
        for (int off = 32; off; off >>= 1) a += __shfl_xor(a, off);
        if (lid == 0) Y[(size_t)tp * DOUT + wv] = a + Wr[NRES];
    };

    for (int t = 0; ; ++t) {
        // ---- barrier: wait until every block published step t-1 ----
        if (t > 0) {
            if (wv == 0) {                      // wave 0 polls all 128 flags
                const int* fb = flags + ((t - 1) & 3) * NBLK;
                int spins = 0;
                for (;;) {
                    const int f0 = __hip_atomic_load(fb + lid, __ATOMIC_RELAXED,
                                                     __HIP_MEMORY_SCOPE_AGENT);
                    const int f1 = __hip_atomic_load(fb + lid + 64, __ATOMIC_RELAXED,
                                                     __HIP_MEMORY_SCOPE_AGENT);
                    if (__all((f0 == t) & (f1 == t))) break;
                    if (++spins > SPIN_LIMIT) {         // watchdog: ~0.25 s max
                        if (lid == 0) bail_s = 1;
                        break;
                    }
                    __builtin_amdgcn_s_sleep(1);        // ~64 cy fabric backoff
                }
                __threadfence();                // acquire: inv L1/L2 (cross-XCD)
            }
            __syncthreads();
            if (bail_s) break;                  // pathology -> clean exit
        }

        // ---- stage x_{t-1} (zeros at t==0); 512 threads x float4 = 8 KB ----
        if (t == 0) {
            ((float4*)x_lds)[tid] = make_float4(0.f, 0.f, 0.f, 0.f);
        } else {
            ((float4*)x_lds)[tid] =
                ((const float4*)(xbuf + ((t - 1) & 1) * NRES))[tid];
        }
        if (t < T_STEPS && tid < DIN) xin_lds[tid] = xin_reg;  // prefetched
        __syncthreads();

        if (t == T_STEPS) {                     // epilogue: Y_{T-1} only
            if (b == ((t - 1) & (NBLK - 1))) readout(t - 1);
            break;
        }

        // ---- matvec: wave wv computes rows 2wv, 2wv+1 ----
        const int r0 = wv * 2, r1 = r0 + 1;
        float acc0 = 0.f, acc1 = 0.f;
        #pragma unroll
        for (int k = 0; k < NRES / 64; ++k) {
            const float xv = x_lds[lid + 64 * k];
            acc0 += W_lds[r0][lid + 64 * k] * xv;
            acc1 += W_lds[r1][lid + 64 * k] * xv;
        }
        #pragma unroll
        for (int off = 32; off; off >>= 1) {
            acc0 += __shfl_xor(acc0, off);
            acc1 += __shfl_xor(acc1, off);
        }
        if (lid == 0 || lid == 32) {
            const int   rl = (lid == 0) ? r0 : r1;
            const float s  = (lid == 0) ? acc0 : acc1;
            float u = b_lds[rl];
            #pragma unroll
            for (int j = 0; j < DIN; ++j) u += Win_lds[rl][j] * xin_lds[j];
            xbuf[(t & 1) * NRES + row0 + rl] =
                OML * x_lds[row0 + rl] + LEAK * tanhf(u + s);
        }
        __syncthreads();   // all slice stores issued before publish

        // ---- publish: agent-scope release store (writes back L2 so the
        //      plain xbuf stores above become visible to other XCDs) ----
        if (tid == 0)
            __hip_atomic_store(&flags[(t & 3) * NBLK + b], t + 1,
                               __ATOMIC_RELEASE, __HIP_MEMORY_SCOPE_AGENT);

        // ---- prefetch inputs[t+1]: issued now, consumed next stage phase;
        //      load latency hides under the poll loop ----
        if (tid < DIN && t + 1 < T_STEPS)
            xin_reg = inputs[(size_t)(t + 1) * DIN + tid];

        // ---- rotating readout of Y_{t-1}; hidden under barrier latency ----
        if (t > 0 && b == ((t - 1) & (NBLK - 1))) readout(t - 1);
    }
}

extern "C" void kernel_launch(void* const* d_in, const int* in_sizes, int n_in,
                              void* d_out, int out_size, void* d_ws, size_t ws_size,
                              hipStream_t stream) {
    const float* inputs = (const float*)d_in[0];
    const float* W_in   = (const float*)d_in[1];
    const float* W      = (const float*)d_in[2];
    const float* bvec   = (const float*)d_in[3];
    const float* W_out  = (const float*)d_in[4];
    float* Y = (float*)d_out;

    int*   flags = (int*)d_ws;                 // 4*128*4 B = 2 KB, no init needed
    float* xbuf  = (float*)(flags + 4 * NBLK); // 16 KB, fully written before read

    esn_persistent<<<NBLK, NTHR, 0, stream>>>(inputs, W_in, W, bvec, W_out,
                                              Y, flags, xbuf);
}

// Round 10
// 64900.000 us; speedup vs baseline: 1.9311x; 1.9311x over previous
//
#include <hip/hip_runtime.h>
#include <math.h>

// Leaky-integrator ESN, persistent kernel, SELF-VALIDATING TAGGED-DATA sync.
//   x_t = 0.1*x_{t-1} + 0.9*tanh(W_in u_t + W x_{t-1} + b);  Y_t = W_out [x_t;1]
//
// R5 post-mortem: flag barrier + fence + separate gather = ~4 serialized fabric
// round trips -> 7.6 us/step, VALUBusy 3%. R6: each x element is published as
// one 8-B agent-scope atomic {tag=step+1 | fp32 bits}. Readers poll the tagged
// array itself (4 slots/thread, reload only stale slots); a fresh tag means the
// VALUE arrived in the same load -> observe+gather merged into ONE round trip.
// No flags, no release, no threadfence (fixes R5's wave0-only-fence hazard).
// Two parities suffice: a writer reaches parity reuse only after all blocks'
// reads of it completed (induction re-audited). Tag values 1..16385 never
// collide with 0xAAAAAAAA poison; parity-0 fully written at t=0 before any
// read. Watchdog folded into the __syncthreads_and collective so bail is
// block-uniform (no barrier mismatch, no hang -> wrong answer + counters).
// [Resubmitted unchanged: R6-R9 benches all died at GPU acquisition,
//  pre-device; one blind edit would contaminate attribution of the first
//  post-redesign measurement.]

#define T_STEPS 16384
#define NRES    2048
#define DIN     8
#define DOUT    8
#define NBLK    128
#define NTHR    512
#define ROWS    16                 // NRES / NBLK
#define SLOTS   4                  // NRES / NTHR
#define LEAK    0.9f
#define OML     0.1f
#define ROUND_LIMIT 300000         // ~0.3 s of poll rounds; never hit if healthy

typedef unsigned long long u64;

__launch_bounds__(NTHR, 1)
__global__ void esn_persistent(const float* __restrict__ inputs,
                               const float* __restrict__ W_in,
                               const float* __restrict__ W,
                               const float* __restrict__ bvec,
                               const float* __restrict__ W_out,
                               float* __restrict__ Y,
                               u64*   __restrict__ xt)    // [2][NRES] tagged x
{
    __shared__ float W_lds[ROWS][NRES];   // 128 KB: this block's rows of W
    __shared__ float x_lds[NRES];         // 8 KB: full x_{t-1}
    __shared__ float xnew_lds[ROWS];
    __shared__ float xin_lds[DIN];
    __shared__ float Win_lds[ROWS][DIN];
    __shared__ float b_lds[ROWS];

    const int b    = blockIdx.x;
    const int tid  = threadIdx.x;
    const int lid  = tid & 63;
    const int wv   = tid >> 6;            // wave 0..7
    const int row0 = b * ROWS;

    // ---- one-time staging: W rows, W_in rows, bias ----
    #pragma unroll
    for (int i = 0; i < ROWS * (NRES / 4) / NTHR; ++i) {       // 16 iters
        const int idx = i * NTHR + tid;
        const int r = idx >> 9, c = idx & 511;                 // NRES/4 = 512
        ((float4*)&W_lds[r][0])[c] =
            ((const float4*)(W + (size_t)(row0 + r) * NRES))[c];
    }
    if (tid < ROWS * DIN)
        Win_lds[tid >> 3][tid & 7] = W_in[(row0 + (tid >> 3)) * DIN + (tid & 7)];
    if (tid < ROWS) b_lds[tid] = bvec[row0 + tid];

    float xin_reg = (tid < DIN) ? inputs[tid] : 0.f;   // step-0 input prefetch

    // readout of Y[tp] from x_lds (must hold x_tp); wave wv -> output wv.
    auto readout = [&](int tp) {
        const float* Wr = W_out + (size_t)wv * (NRES + 1);
        float a = 0.f;
        #pragma unroll
        for (int k = 0; k < NRES / 64; ++k)
            a += Wr[lid + 64 * k] * x_lds[lid + 64 * k];
        #pragma unroll
        for (int off = 32; off; off >>= 1) a += __shfl_xor(a, off);
        if (lid == 0) Y[(size_t)tp * DOUT + wv] = a + Wr[NRES];
    };

    for (int t = 0; ; ++t) {
        // ---- poll-gather x_{t-1}: tags==t in parity (t-1)&1 ----
        if (t > 0) {
            const u64* src = xt + (size_t)((t - 1) & 1) * NRES;
            u64 v0 = 0, v1 = 0, v2 = 0, v3 = 0;
            int ok0 = 0, ok1 = 0, ok2 = 0, ok3 = 0;
            int rounds = 0;
            for (;;) {
                if (!ok0) { v0 = __hip_atomic_load(src + tid,            __ATOMIC_RELAXED, __HIP_MEMORY_SCOPE_AGENT); ok0 = ((int)(v0 >> 32) == t); }
                if (!ok1) { v1 = __hip_atomic_load(src + tid + NTHR,     __ATOMIC_RELAXED, __HIP_MEMORY_SCOPE_AGENT); ok1 = ((int)(v1 >> 32) == t); }
                if (!ok2) { v2 = __hip_atomic_load(src + tid + 2 * NTHR, __ATOMIC_RELAXED, __HIP_MEMORY_SCOPE_AGENT); ok2 = ((int)(v2 >> 32) == t); }
                if (!ok3) { v3 = __hip_atomic_load(src + tid + 3 * NTHR, __ATOMIC_RELAXED, __HIP_MEMORY_SCOPE_AGENT); ok3 = ((int)(v3 >> 32) == t); }
                ++rounds;
                const int okall = ok0 & ok1 & ok2 & ok3;
                // collective exit: uniform across block even with wave skew
                // (ok flags are monotone within a step -> races only help)
                if (__syncthreads_and(okall | (rounds > ROUND_LIMIT))) break;
            }
            if (!__syncthreads_and(ok0 & ok1 & ok2 & ok3))
                break;                         // watchdog: uniform clean exit
            // data arrived with the tags -- stage straight to LDS
            x_lds[tid]            = __uint_as_float((unsigned)v0);
            x_lds[tid + NTHR]     = __uint_as_float((unsigned)v1);
            x_lds[tid + 2 * NTHR] = __uint_as_float((unsigned)v2);
            x_lds[tid + 3 * NTHR] = __uint_as_float((unsigned)v3);
        } else {
            ((float4*)x_lds)[tid] = make_float4(0.f, 0.f, 0.f, 0.f);
        }
        if (t < T_STEPS && tid < DIN) xin_lds[tid] = xin_reg;  // prefetched
        __syncthreads();

        if (t == T_STEPS) {                    // epilogue: Y_{T-1} only
            if (b == ((t - 1) & (NBLK - 1))) readout(t - 1);
            break;
        }

        // ---- matvec: wave wv computes rows 2wv, 2wv+1 (same order as R5) ----
        const int r0 = wv * 2, r1 = r0 + 1;
        float acc0 = 0.f, acc1 = 0.f;
        #pragma unroll
        for (int k = 0; k < NRES / 64; ++k) {
            const float xv = x_lds[lid + 64 * k];
            acc0 += W_lds[r0][lid + 64 * k] * xv;
            acc1 += W_lds[r1][lid + 64 * k] * xv;
        }
        #pragma unroll
        for (int off = 32; off; off >>= 1) {
            acc0 += __shfl_xor(acc0, off);
            acc1 += __shfl_xor(acc1, off);
        }
        if (lid == 0 || lid == 32) {
            const int   rl = (lid == 0) ? r0 : r1;
            const float s  = (lid == 0) ? acc0 : acc1;
            float u = b_lds[rl];
            #pragma unroll
            for (int j = 0; j < DIN; ++j) u += Win_lds[rl][j] * xin_lds[j];
            xnew_lds[rl] = OML * x_lds[row0 + rl] + LEAK * tanhf(u + s);
        }
        __syncthreads();

        // ---- publish: wave 0 stores 16 tagged records (128 B coalesced,
        //      fire-and-forget; the tag IS the synchronization) ----
        if (wv == 0 && lid < ROWS) {
            const u64 rec = ((u64)(unsigned)(t + 1) << 32)
                          | (u64)__float_as_uint(xnew_lds[lid]);
            __hip_atomic_store(xt + (size_t)(t & 1) * NRES + row0 + lid, rec,
                               __ATOMIC_RELAXED, __HIP_MEMORY_SCOPE_AGENT);
        }

        // ---- off-critical-path work: input prefetch + rotating readout ----
        if (tid < DIN && t + 1 < T_STEPS)
            xin_reg = inputs[(size_t)(t + 1) * DIN + tid];
        if (t > 0 && b == ((t - 1) & (NBLK - 1))) readout(t - 1);
    }
}

extern "C" void kernel_launch(void* const* d_in, const int* in_sizes, int n_in,
                              void* d_out, int out_size, void* d_ws, size_t ws_size,
                              hipStream_t stream) {
    const float* inputs = (const float*)d_in[0];
    const float* W_in   = (const float*)d_in[1];
    const float* W      = (const float*)d_in[2];
    const float* bvec   = (const float*)d_in[3];
    const float* W_out  = (const float*)d_in[4];
    float* Y = (float*)d_out;

    u64* xt = (u64*)d_ws;   // 2 * 2048 * 8 B = 32 KB; no init needed (tags
                            // 1..16385 never equal 0xAAAAAAAA poison; parity 0
                            // fully written at step 0 before any read)

    esn_persistent<<<NBLK, NTHR, 0, stream>>>(inputs, W_in, W, bvec, W_out,
                                              Y, xt);
}

// Round 12
// 56200.702 us; speedup vs baseline: 2.2300x; 1.1548x over previous
//
#include <hip/hip_runtime.h>
#include <math.h>

// Leaky-integrator ESN, persistent kernel, SELF-VALIDATING TAGGED-DATA sync.
//   x_t = 0.1*x_{t-1} + 0.9*tanh(W_in u_t + W x_{t-1} + b);  Y_t = W_out [x_t;1]
//
// Ladder: R5 flag-barrier 125.3 ms -> R10 tagged-data 64.9 ms (3.8 us/step).
// R10 post-mortem: polls are MALL-served (FETCH ~1.1 GB, not HBM); residual
// cost is latency: publish flight + POLL-ROUND QUANTIZATION (every round ended
// in __syncthreads_and, so observation advanced in block-lockstep ~1 us
// granules). R11: PER-THREAD INDEPENDENT SPIN — each thread spins only on its
// own 4 slots (reload stale only), stages to LDS when *it* finishes, then ONE
// collective __syncthreads_and vote (doubles as stage-visibility barrier; one
// fewer barrier/step than R10). Tag {step+1 | fp32 bits} in a single 8-B
// agent-scope atomic: fresh tag => value arrived in the same load.
// Invariants unchanged: 2-parity reuse gated transitively by completed reads;
// tags 1..16385 never equal 0xAAAAAAAA poison; parity-0 fully written at t=0;
// bounded spin + uniform vote -> pathology = wrong answer + counters, no hang.
// [Resubmitted unchanged: R11 bench died at GPU acquisition, pre-device.]

#define T_STEPS 16384
#define NRES    2048
#define DIN     8
#define DOUT    8
#define NBLK    128
#define NTHR    512
#define ROWS    16                 // NRES / NBLK
#define LEAK    0.9f
#define OML     0.1f
#define SPIN_LIMIT 150000          // ~0.1 s of dependent reloads; healthy ~2-5

typedef unsigned long long u64;

#define AL(p) __hip_atomic_load((p), __ATOMIC_RELAXED, __HIP_MEMORY_SCOPE_AGENT)

__launch_bounds__(NTHR, 1)
__global__ void esn_persistent(const float* __restrict__ inputs,
                               const float* __restrict__ W_in,
                               const float* __restrict__ W,
                               const float* __restrict__ bvec,
                               const float* __restrict__ W_out,
                               float* __restrict__ Y,
                               u64*   __restrict__ xt)    // [2][NRES] tagged x
{
    __shared__ float W_lds[ROWS][NRES];   // 128 KB: this block's rows of W
    __shared__ float x_lds[NRES];         // 8 KB: full x_{t-1}
    __shared__ float xnew_lds[ROWS];
    __shared__ float xin_lds[DIN];
    __shared__ float Win_lds[ROWS][DIN];
    __shared__ float b_lds[ROWS];

    const int b    = blockIdx.x;
    const int tid  = threadIdx.x;
    const int lid  = tid & 63;
    const int wv   = tid >> 6;            // wave 0..7
    const int row0 = b * ROWS;

    // ---- one-time staging: W rows, W_in rows, bias ----
    #pragma unroll
    for (int i = 0; i < ROWS * (NRES / 4) / NTHR; ++i) {       // 16 iters
        const int idx = i * NTHR + tid;
        const int r = idx >> 9, c = idx & 511;                 // NRES/4 = 512
        ((float4*)&W_lds[r][0])[c] =
            ((const float4*)(W + (size_t)(row0 + r) * NRES))[c];
    }
    if (tid < ROWS * DIN)
        Win_lds[tid >> 3][tid & 7] = W_in[(row0 + (tid >> 3)) * DIN + (tid & 7)];
    if (tid < ROWS) b_lds[tid] = bvec[row0 + tid];

    float xin_reg = (tid < DIN) ? inputs[tid] : 0.f;   // step-0 input prefetch

    // readout of Y[tp] from x_lds (must hold x_tp); wave wv -> output wv.
    auto readout = [&](int tp) {
        const float* Wr = W_out + (size_t)wv * (NRES + 1);
        float a = 0.f;
        #pragma unroll
        for (int k = 0; k < NRES / 64; ++k)
            a += Wr[lid + 64 * k] * x_lds[lid + 64 * k];
        #pragma unroll
        for (int off = 32; off; off >>= 1) a += __shfl_xor(a, off);
        if (lid == 0) Y[(size_t)tp * DOUT + wv] = a + Wr[NRES];
    };

    for (int t = 0; ; ++t) {
        // ---- poll-gather x_{t-1}: PER-THREAD spin on own 4 slots ----
        int okall = 1;
        if (t > 0) {
            const u64* src = xt + (size_t)((t - 1) & 1) * NRES;
            u64 v0 = 0, v1 = 0, v2 = 0, v3 = 0;
            int ok0 = 0, ok1 = 0, ok2 = 0, ok3 = 0;
            for (int it = 0; !(ok0 & ok1 & ok2 & ok3) && it < SPIN_LIMIT; ++it) {
                if (!ok0) { v0 = AL(src + tid);            ok0 = ((int)(v0 >> 32) == t); }
                if (!ok1) { v1 = AL(src + tid + NTHR);     ok1 = ((int)(v1 >> 32) == t); }
                if (!ok2) { v2 = AL(src + tid + 2 * NTHR); ok2 = ((int)(v2 >> 32) == t); }
                if (!ok3) { v3 = AL(src + tid + 3 * NTHR); ok3 = ((int)(v3 >> 32) == t); }
            }
            // stage immediately (values valid iff ok*; vote below gates use)
            x_lds[tid]            = __uint_as_float((unsigned)v0);
            x_lds[tid + NTHR]     = __uint_as_float((unsigned)v1);
            x_lds[tid + 2 * NTHR] = __uint_as_float((unsigned)v2);
            x_lds[tid + 3 * NTHR] = __uint_as_float((unsigned)v3);
            okall = ok0 & ok1 & ok2 & ok3;
        } else {
            ((float4*)x_lds)[tid] = make_float4(0.f, 0.f, 0.f, 0.f);
        }
        if (t < T_STEPS && tid < DIN) xin_lds[tid] = xin_reg;  // prefetched

        // ONE barrier: stage-visibility + watchdog vote (uniform exit)
        if (!__syncthreads_and(okall)) break;

        if (t == T_STEPS) {                    // epilogue: Y_{T-1} only
            if (b == ((t - 1) & (NBLK - 1))) readout(t - 1);
            break;
        }

        // ---- matvec: wave wv computes rows 2wv, 2wv+1 (same order as R5) ----
        const int r0 = wv * 2, r1 = r0 + 1;
        float acc0 = 0.f, acc1 = 0.f;
        #pragma unroll
        for (int k = 0; k < NRES / 64; ++k) {
            const float xv = x_lds[lid + 64 * k];
            acc0 += W_lds[r0][lid + 64 * k] * xv;
            acc1 += W_lds[r1][lid + 64 * k] * xv;
        }
        #pragma unroll
        for (int off = 32; off; off >>= 1) {
            acc0 += __shfl_xor(acc0, off);
            acc1 += __shfl_xor(acc1, off);
        }
        if (lid == 0 || lid == 32) {
            const int   rl = (lid == 0) ? r0 : r1;
            const float s  = (lid == 0) ? acc0 : acc1;
            float u = b_lds[rl];
            #pragma unroll
            for (int j = 0; j < DIN; ++j) u += Win_lds[rl][j] * xin_lds[j];
            xnew_lds[rl] = OML * x_lds[row0 + rl] + LEAK * tanhf(u + s);
        }
        __syncthreads();                       // xnew_lds visible to wave 0

        // ---- publish: wave 0 stores 16 tagged records (128 B coalesced,
        //      fire-and-forget; the tag IS the synchronization) ----
        if (wv == 0 && lid < ROWS) {
            const u64 rec = ((u64)(unsigned)(t + 1) << 32)
                          | (u64)__float_as_uint(xnew_lds[lid]);
            __hip_atomic_store(xt + (size_t)(t & 1) * NRES + row0 + lid, rec,
                               __ATOMIC_RELAXED, __HIP_MEMORY_SCOPE_AGENT);
        }

        // ---- off-critical-path work: input prefetch + rotating readout ----
        if (tid < DIN && t + 1 < T_STEPS)
            xin_reg = inputs[(size_t)(t + 1) * DIN + tid];
        if (t > 0 && b == ((t - 1) & (NBLK - 1))) readout(t - 1);
    }
}

extern "C" void kernel_launch(void* const* d_in, const int* in_sizes, int n_in,
                              void* d_out, int out_size, void* d_ws, size_t ws_size,
                              hipStream_t stream) {
    const float* inputs = (const float*)d_in[0];
    const float* W_in   = (const float*)d_in[1];
    const float* W      = (const float*)d_in[2];
    const float* bvec   = (const float*)d_in[3];
    const float* W_out  = (const float*)d_in[4];
    float* Y = (float*)d_out;

    u64* xt = (u64*)d_ws;   // 2 * 2048 * 8 B = 32 KB; no init needed (tags
                            // 1..16385 never equal 0xAAAAAAAA poison; parity 0
                            // fully written at step 0 before any read)

    esn_persistent<<<NBLK, NTHR, 0, stream>>>(inputs, W_in, W, bvec, W_out,
                                              Y, xt);
}

// Round 13
// 55772.101 us; speedup vs baseline: 2.2472x; 1.0077x over previous
//
#include <hip/hip_runtime.h>
#include <math.h>

// Leaky-integrator ESN, persistent kernel, tagged-data sync, direct publish.
//   x_t = 0.1*x_{t-1} + 0.9*tanh(W_in u_t + W x_{t-1} + b);  Y_t = W_out [x_t;1]
//
// Ladder: R5 flag-barrier 125.3 -> R10 tagged-data 64.9 -> R12 per-thread-spin
// 56.2 (steady 53.2 ms, 3.25 us/step). R12 counters: VALUBusy 10.9%, FETCH
// ~1.1 GB (polls MALL-served) -> residual is publish-path + fabric latency.
// R13: DIRECT PER-WAVE PUBLISH — reduce lanes (lid 0/32) store their own 2
// tagged records right after tanh: removes xnew_lds round trip, the publish
// barrier (slowest-wave wait), and wave-0 re-issue from the critical path.
// The WAR hazard this exposes (fast wave staging x_t over x_{t-1} mid-read)
// is fixed by DOUBLE-BUFFERED x_lds/xin_lds by step parity (+8 KB LDS).
// Parity-buffer reuse at t+2 is poll-gated: passing poll-for-t+2 requires all
// waves published t+2, which is after their t+1 matvec, i.e. after all reads
// of buffer p_t (audited for matvec, readout, xin). ONE barrier per step
// (stage visibility + watchdog vote). Tag {step+1 | fp32 bits} in one 8-B
// agent-scope atomic; tags 1..16385 never equal 0xAA poison; parity-0 fully
// written at t=0; bounded spin + uniform vote -> no-hang guarantee.

#define T_STEPS 16384
#define NRES    2048
#define DIN     8
#define DOUT    8
#define NBLK    128
#define NTHR    512
#define ROWS    16                 // NRES / NBLK
#define LEAK    0.9f
#define OML     0.1f
#define SPIN_LIMIT 150000          // ~0.1 s of dependent reloads; healthy ~2-5

typedef unsigned long long u64;

#define AL(p) __hip_atomic_load((p), __ATOMIC_RELAXED, __HIP_MEMORY_SCOPE_AGENT)

__launch_bounds__(NTHR, 1)
__global__ void esn_persistent(const float* __restrict__ inputs,
                               const float* __restrict__ W_in,
                               const float* __restrict__ W,
                               const float* __restrict__ bvec,
                               const float* __restrict__ W_out,
                               float* __restrict__ Y,
                               u64*   __restrict__ xt)    // [2][NRES] tagged x
{
    __shared__ float W_lds[ROWS][NRES];   // 128 KB: this block's rows of W
    __shared__ float x_lds[2][NRES];      // 16 KB: x double buffer (parity)
    __shared__ float xin_lds[2][DIN];
    __shared__ float Win_lds[ROWS][DIN];
    __shared__ float b_lds[ROWS];

    const int b    = blockIdx.x;
    const int tid  = threadIdx.x;
    const int lid  = tid & 63;
    const int wv   = tid >> 6;            // wave 0..7
    const int row0 = b * ROWS;

    // ---- one-time staging: W rows, W_in rows, bias ----
    #pragma unroll
    for (int i = 0; i < ROWS * (NRES / 4) / NTHR; ++i) {       // 16 iters
        const int idx = i * NTHR + tid;
        const int r = idx >> 9, c = idx & 511;                 // NRES/4 = 512
        ((float4*)&W_lds[r][0])[c] =
            ((const float4*)(W + (size_t)(row0 + r) * NRES))[c];
    }
    if (tid < ROWS * DIN)
        Win_lds[tid >> 3][tid & 7] = W_in[(row0 + (tid >> 3)) * DIN + (tid & 7)];
    if (tid < ROWS) b_lds[tid] = bvec[row0 + tid];

    float xin_reg = (tid < DIN) ? inputs[tid] : 0.f;   // step-0 input prefetch

    // readout of Y[tp] from buffer xb (must hold x_tp); wave wv -> output wv.
    auto readout = [&](int tp, const float* xb) {
        const float* Wr = W_out + (size_t)wv * (NRES + 1);
        float a = 0.f;
        #pragma unroll
        for (int k = 0; k < NRES / 64; ++k)
            a += Wr[lid + 64 * k] * xb[lid + 64 * k];
        #pragma unroll
        for (int off = 32; off; off >>= 1) a += __shfl_xor(a, off);
        if (lid == 0) Y[(size_t)tp * DOUT + wv] = a + Wr[NRES];
    };

    for (int t = 0; ; ++t) {
        const int p = (t + 1) & 1;            // staging parity for x_{t-1}
        float* xb = &x_lds[p][0];

        // ---- poll-gather x_{t-1}: per-thread spin on own 4 tagged slots ----
        int okall = 1;
        if (t > 0) {
            const u64* src = xt + (size_t)((t - 1) & 1) * NRES;
            u64 v0 = 0, v1 = 0, v2 = 0, v3 = 0;
            int ok0 = 0, ok1 = 0, ok2 = 0, ok3 = 0;
            for (int it = 0; !(ok0 & ok1 & ok2 & ok3) && it < SPIN_LIMIT; ++it) {
                if (!ok0) { v0 = AL(src + tid);            ok0 = ((int)(v0 >> 32) == t); }
                if (!ok1) { v1 = AL(src + tid + NTHR);     ok1 = ((int)(v1 >> 32) == t); }
                if (!ok2) { v2 = AL(src + tid + 2 * NTHR); ok2 = ((int)(v2 >> 32) == t); }
                if (!ok3) { v3 = AL(src + tid + 3 * NTHR); ok3 = ((int)(v3 >> 32) == t); }
            }
            xb[tid]            = __uint_as_float((unsigned)v0);
            xb[tid + NTHR]     = __uint_as_float((unsigned)v1);
            xb[tid + 2 * NTHR] = __uint_as_float((unsigned)v2);
            xb[tid + 3 * NTHR] = __uint_as_float((unsigned)v3);
            okall = ok0 & ok1 & ok2 & ok3;
        } else {
            ((float4*)xb)[tid] = make_float4(0.f, 0.f, 0.f, 0.f);
        }
        if (t < T_STEPS && tid < DIN) xin_lds[p][tid] = xin_reg;  // prefetched

        // ONE barrier per step: stage visibility + watchdog vote (uniform)
        if (!__syncthreads_and(okall)) break;

        if (t == T_STEPS) {                    // epilogue: Y_{T-1} only
            if (b == ((t - 1) & (NBLK - 1))) readout(t - 1, xb);
            break;
        }

        // ---- matvec: wave wv computes rows 2wv, 2wv+1 ----
        const int r0 = wv * 2, r1 = r0 + 1;
        float acc0 = 0.f, acc1 = 0.f;
        #pragma unroll
        for (int k = 0; k < NRES / 64; ++k) {
            const float xv = xb[lid + 64 * k];
            acc0 += W_lds[r0][lid + 64 * k] * xv;
            acc1 += W_lds[r1][lid + 64 * k] * xv;
        }
        #pragma unroll
        for (int off = 32; off; off >>= 1) {
            acc0 += __shfl_xor(acc0, off);
            acc1 += __shfl_xor(acc1, off);
        }

        // ---- DIRECT publish from the reduce lanes: each wave stores its own
        //      2 tagged records the moment they're ready (fire-and-forget) ----
        if (lid == 0 || lid == 32) {
            const int   rl = (lid == 0) ? r0 : r1;
            const float s  = (lid == 0) ? acc0 : acc1;
            float u = b_lds[rl];
            #pragma unroll
            for (int j = 0; j < DIN; ++j) u += Win_lds[rl][j] * xin_lds[p][j];
            const float xn = OML * xb[row0 + rl] + LEAK * tanhf(u + s);
            const u64 rec = ((u64)(unsigned)(t + 1) << 32)
                          | (u64)__float_as_uint(xn);
            __hip_atomic_store(xt + (size_t)(t & 1) * NRES + row0 + rl, rec,
                               __ATOMIC_RELAXED, __HIP_MEMORY_SCOPE_AGENT);
        }

        // ---- off-critical-path work: input prefetch + rotating readout ----
        if (tid < DIN && t + 1 < T_STEPS)
            xin_reg = inputs[(size_t)(t + 1) * DIN + tid];
        if (t > 0 && b == ((t - 1) & (NBLK - 1))) readout(t - 1, xb);
    }
}

extern "C" void kernel_launch(void* const* d_in, const int* in_sizes, int n_in,
                              void* d_out, int out_size, void* d_ws, size_t ws_size,
                              hipStream_t stream) {
    const float* inputs = (const float*)d_in[0];
    const float* W_in   = (const float*)d_in[1];
    const float* W      = (const float*)d_in[2];
    const float* bvec   = (const float*)d_in[3];
    const float* W_out  = (const float*)d_in[4];
    float* Y = (float*)d_out;

    u64* xt = (u64*)d_ws;   // 2 * 2048 * 8 B = 32 KB; no init needed (tags
                            // 1..16385 never equal 0xAAAAAAAA poison; parity 0
                            // fully written at step 0 before any read)

    esn_persistent<<<NBLK, NTHR, 0, stream>>>(inputs, W_in, W, bvec, W_out,
                                              Y, xt);
}